// Round 7
// baseline (631.820 us; speedup 1.0000x reference)
//
#include <hip/hip_runtime.h>
#include <stdint.h>

#define T_DIM  128
#define TSTEPS 127
#define BATCH  512
#define DDATA  512
#define HHID   512
#define BH     262144   // BATCH*HHID
#define CPAD   132      // 16B-aligned rows; conflicts measured negligible (r6)

typedef _Float16 f16;
typedef _Float16 f16x8 __attribute__((ext_vector_type(8)));
typedef float    f32x4 __attribute__((ext_vector_type(4)));
typedef unsigned int u32x2 __attribute__((ext_vector_type(2)));

#define MFMA16 __builtin_amdgcn_mfma_f32_16x16x32_f16

// asm loads: results are asm-defined -> non-rematerializable (stay in regs)
__device__ __forceinline__ f16x8 ld16(const f16* p) {          // plain cached
  f16x8 r;
  asm volatile("global_load_dwordx4 %0, %1, off" : "=v"(r) : "v"(p));
  return r;
}
__device__ __forceinline__ f16x8 ld16cc(const f16* p) {        // LLC-coherent (proven r4/r6)
  f16x8 r;
  asm volatile("global_load_dwordx4 %0, %1, off sc0 sc1" : "=v"(r) : "v"(p));
  return r;
}
__device__ __forceinline__ void st8cc(void* p, u32x2 v) {      // LLC-coherent 8B store
  asm volatile("global_store_dwordx2 %0, %1, off sc0 sc1" :: "v"(p), "v"(v) : "memory");
}

// lgkm-only barrier: protects LDS reuse WITHOUT draining vmcnt (global ops
// stay in flight across it; sentinel protocol owns global visibility).
#define BAR_LGKM do { asm volatile("s_waitcnt lgkmcnt(0)\n\ts_barrier" ::: "memory"); } while (0)

// ---------------------------------------------------------------------------
// W16B: f16 B-fragments, flat [nb16][kq4][ch2][fi=ks*4+nf 32][lane64][8]
// col16 = lane&15 = hm*4+g ; k = kq*256 + ks*32 + (lane>>4)*8 + e
// h column hg = nb*32 + (ch*4+nf)*4 + hm ; gate row R = g*512 + hg
// ---------------------------------------------------------------------------
__global__ void k_prep_w(const float* __restrict__ W_ih, const float* __restrict__ W_hh,
                         f16* __restrict__ W16B) {
  int d = blockIdx.x * blockDim.x + threadIdx.x;   // 0..262143
  int lane = d & 63;
  int fi   = (d >> 6) & 31;
  int ch   = (d >> 11) & 1;
  int kq   = (d >> 12) & 3;
  int nbv  = d >> 14;
  int ks = fi >> 2, nf = fi & 3;
  int col16 = lane & 15, lk2 = lane >> 4;
  int hm = col16 >> 2, g = col16 & 3;
  int hg = nbv * 32 + (ch * 4 + nf) * 4 + hm;
  int R = g * 512 + hg;
  int k = kq * 256 + ks * 32 + lk2 * 8;
  const float* src = (k < 512) ? (W_ih + (size_t)R * 512 + k)
                               : (W_hh + (size_t)R * 512 + (k - 512));
  f16x8 o;
#pragma unroll
  for (int e = 0; e < 8; e++) o[e] = (f16)src[e];
  *(f16x8*)(W16B + (size_t)d * 8) = o;
}

__global__ void k_prep_b(const float* __restrict__ b_ih, const float* __restrict__ b_hh,
                         float* __restrict__ biasR) {
  int r = blockIdx.x * blockDim.x + threadIdx.x;
  if (r < 2048) biasR[r] = b_ih[r] + b_hh[r];
}

// X [B, T, D] f32 -> XT [t][kc(64)][row(512)][8] f16, LDS-transposed so both
// global sides are fully coalesced (old version read 32B granules at 256KB
// stride -> ~2x HBM read over-fetch).
__global__ void k_prep_x(const float* __restrict__ X, f16* __restrict__ XT) {
  __shared__ f16 Ls[32][516];          // pad 4 f16 (stride/4 == 2 mod 32)
  const int t = blockIdx.x;            // 0..126
  const int rb = blockIdx.y;           // 0..15 (32-row block)
  const int tid = threadIdx.x;         // 256
  const int rloc = tid >> 5;           // 0..7
  const int dc = (tid & 31) * 16;      // d start
#pragma unroll
  for (int it = 0; it < 4; it++) {
    int row = it * 8 + rloc;
    const float* src = X + (size_t)(rb * 32 + row) * (T_DIM * DDATA)
                         + (size_t)t * DDATA + dc;
    f32x4 a0 = *(const f32x4*)(src);
    f32x4 a1 = *(const f32x4*)(src + 4);
    f32x4 a2 = *(const f32x4*)(src + 8);
    f32x4 a3 = *(const f32x4*)(src + 12);
    f16x8 h0, h1;
#pragma unroll
    for (int e = 0; e < 4; e++) {
      h0[e] = (f16)a0[e]; h0[4 + e] = (f16)a1[e];
      h1[e] = (f16)a2[e]; h1[4 + e] = (f16)a3[e];
    }
    *(f16x8*)&Ls[row][dc] = h0;
    *(f16x8*)&Ls[row][dc + 8] = h1;
  }
  __syncthreads();
#pragma unroll
  for (int it = 0; it < 8; it++) {
    int chunk = it * 256 + tid;        // kc*32 + row
    int kc = chunk >> 5, row = chunk & 31;
    f16x8 v = *(const f16x8*)&Ls[row][kc * 8];
    *(f16x8*)(XT + (size_t)t * BH + (size_t)kc * 4096
              + (size_t)(rb * 32 + row) * 8) = v;
  }
}

// ---------------------------------------------------------------------------
// Persistent LSTM: 256 WGs x 512 thr. Handoff = sentinel protocol: h_all[t>=1]
// pre-poisoned 0xFF (f16 NaN, unreachable); producers just store (sc0sc1, 8B
// atomic granules); consumers load+validate+retry. No flags, no store-ACK
// stall, no atomics on the serial path.
// Waves: w>>1 = kq (K-quarter; 0,1 = x-half, 2,3 = h-half), w&1 = ch.
// ---------------------------------------------------------------------------
__launch_bounds__(512, 1)
__global__ void k_lstm(const f16* __restrict__ XT, f16* __restrict__ h_all,
                       const f16* __restrict__ W16B, const float* __restrict__ biasR) {
  __shared__ float C[4][32][CPAD];     // per-K-quarter partials (~67.6KB)
  __shared__ float BiasS[128];

  const int tid = threadIdx.x, lane = tid & 63, w = tid >> 6;
  const int kq = w >> 1;               // 0..3 (w&1 = ch, encoded in B slice)
  const int wg = blockIdx.x;
  const int mb = (wg & 7) * 2 + ((wg >> 3) & 1);
  const int nb = wg >> 4;
  const int m0 = mb * 32;
  const int l15 = lane & 15, lk = lane >> 4;

  // persistent B fragments: 32 x f16x8 = 128 regs/wave, pinned by asm defs
  f16x8 B[32];
  {
    const f16* wb = W16B + ((size_t)((nb * 4 + kq) * 2 + (w & 1)) * 32) * 512 + lane * 8;
#pragma unroll
    for (int i = 0; i < 32; i++) B[i] = ld16(wb + i * 512);
    asm volatile("s_waitcnt vmcnt(0)" ::: "memory");
    __builtin_amdgcn_sched_barrier(0);
  }
  if (tid < 128) {
    // BiasS[q8*16 + hm*4 + g] = bias[gate g, h-col nb*32 + q8*4 + hm]
    int q8 = tid >> 4, hm = (tid >> 2) & 3, g = tid & 3;
    BiasS[tid] = biasR[g * 512 + nb * 32 + q8 * 4 + hm];
  }
  float c_reg[4] = {0.f, 0.f, 0.f, 0.f};   // cell state (tid<256 meaningful)
  __syncthreads();

#define WAITV(N) asm volatile("s_waitcnt vmcnt(" #N ")" ::: "memory");        \
                 __builtin_amdgcn_sched_barrier(0)
#define MFMA4KS(KS0)                                                          \
    {                                                                         \
      _Pragma("unroll")                                                       \
      for (int s = 0; s < 4; s++) {                                           \
        int ks = KS0 + s;                                                     \
        _Pragma("unroll")                                                     \
        for (int nf = 0; nf < 4; nf++) {                                      \
          acc[0][nf] = MFMA16(R[2 * ks],     B[ks * 4 + nf], acc[0][nf], 0, 0, 0); \
          acc[1][nf] = MFMA16(R[2 * ks + 1], B[ks * 4 + nf], acc[1][nf], 0, 0, 0); \
        }                                                                     \
      }                                                                       \
    }
#define ISSUE_X(T)                                                            \
    {                                                                         \
      const f16* Ab = XT + (size_t)(T) * BH + (size_t)(kq * 32 + lk) * 4096   \
                      + (size_t)(m0 + l15) * 8;                               \
      _Pragma("unroll")                                                       \
      for (int ks = 0; ks < 8; ks++) {                                        \
        R[2 * ks]     = ld16(Ab + (size_t)ks * 16384);                        \
        R[2 * ks + 1] = ld16(Ab + (size_t)ks * 16384 + 128);                  \
      }                                                                       \
    }

  f16x8 R[16];
  if (kq < 2) ISSUE_X(0);              // prologue prefetch for t=0

  for (int t = 0; t < TSTEPS; t++) {
    f32x4 acc[2][4] = {};

    if (kq < 2) {
      // x-half: loads for this t prefetched last iteration (+ drains own store)
      WAITV(0);
      MFMA4KS(0);
      MFMA4KS(4);
      if (t + 1 < TSTEPS) ISSUE_X(t + 1);   // in flight across barriers/epilogue
    } else if (t > 0) {
      // h-half: sentinel-validated load of h[t] (produced by 16 WGs of mb-group)
      const f16* Hb = h_all + (size_t)t * BH + (size_t)((kq - 2) * 32 + lk) * 4096
                      + (size_t)(m0 + l15) * 8;
      int rounds = 0;
      while (true) {
#pragma unroll
        for (int ks = 0; ks < 8; ks++) {
          R[2 * ks]     = ld16cc(Hb + (size_t)ks * 16384);
          R[2 * ks + 1] = ld16cc(Hb + (size_t)ks * 16384 + 128);
        }
        WAITV(0);
        unsigned bad = 0;
#pragma unroll
        for (int i = 0; i < 16; i++) {
          const unsigned* u = (const unsigned*)&R[i];
          bad |= (unsigned)(u[0] == 0xFFFFFFFFu) | (unsigned)(u[2] == 0xFFFFFFFFu);
        }
        if (__all(bad == 0)) break;          // all 8B granules written
        if (++rounds > 4096) break;          // bounded: fail visibly, never hang
        __builtin_amdgcn_s_sleep(1);
      }
      MFMA4KS(0);
      MFMA4KS(4);
    }
    // (kq>=2, t==0: h0 == 0 -> acc stays zero)

    // K-quarter partials -> LDS
#pragma unroll
    for (int mf = 0; mf < 2; mf++)
#pragma unroll
      for (int nf = 0; nf < 4; nf++)
#pragma unroll
        for (int r = 0; r < 4; r++)
          C[kq][mf * 16 + lk * 4 + r][(w & 1) * 64 + nf * 16 + l15] = acc[mf][nf][r];
    BAR_LGKM;   // LDS writes visible; vmcnt NOT drained (prefetch/stores fly)

    // epilogue on x-threads (tid<256): thread -> (row r, h-quad q8*4..+4)
    if (tid < 256) {
      int r = tid >> 3, q8 = tid & 7;
      f32x4 uu[4] = {};
#pragma unroll
      for (int q = 0; q < 4; q++) {
        const f32x4* base = (const f32x4*)&C[q][r][q8 * 16];
        uu[0] += base[0];
        uu[1] += base[1];
        uu[2] += base[2];
        uu[3] += base[3];
      }
      union { f16 h[4]; u32x2 v; } pk;
#pragma unroll
      for (int hm = 0; hm < 4; hm++) {
        float gi = uu[hm][0] + BiasS[q8 * 16 + hm * 4 + 0];
        float gf = uu[hm][1] + BiasS[q8 * 16 + hm * 4 + 1];
        float gg = uu[hm][2] + BiasS[q8 * 16 + hm * 4 + 2];
        float go = uu[hm][3] + BiasS[q8 * 16 + hm * 4 + 3];
        float ii = 1.f / (1.f + __expf(-gi));
        float ff = 1.f / (1.f + __expf(-gf));
        float eg = __expf(-2.f * fabsf(gg));
        float tg = copysignf((1.f - eg) / (1.f + eg), gg);
        float oo = 1.f / (1.f + __expf(-go));
        c_reg[hm] = ff * c_reg[hm] + ii * tg;
        float ec = __expf(-2.f * fabsf(c_reg[hm]));
        float th = copysignf((1.f - ec) / (1.f + ec), c_reg[hm]);
        pk.h[hm] = (f16)(oo * th);
      }
      // h_all layout [kc][row][8]: kc = nb*4 + (q8>>1), 4-f16 half = (q8&1)*4
      f16* dst = h_all + (size_t)(t + 1) * BH
                 + (size_t)(nb * 4 + (q8 >> 1)) * 4096 + (size_t)(m0 + r) * 8
                 + (q8 & 1) * 4;
      st8cc(dst, pk.v);   // no ACK wait: consumers self-validate via sentinel
    }
    BAR_LGKM;   // epilogue LDS reads done -> C reusable next step
  }
#undef WAITV
#undef MFMA4KS
#undef ISSUE_X
}

// ---------------------------------------------------------------------------
// Tail: cosine-similarity attention (h_all is f16)
// ---------------------------------------------------------------------------
__global__ void k_dots(const f16* __restrict__ h_all, float* __restrict__ part) {
  int t = blockIdx.x, s = blockIdx.y;
  const f16x8* ht = (const f16x8*)(h_all + (size_t)t * BH) + (size_t)s * 8192;
  const f16x8* hf = (const f16x8*)(h_all + (size_t)127 * BH) + (size_t)s * 8192;
  float sn = 0.f, sq = 0.f;
  for (int i = threadIdx.x; i < 8192; i += 256) {
    f16x8 a = ht[i], b = hf[i];
#pragma unroll
    for (int e = 0; e < 8; e++) {
      float fa = (float)a[e], fb = (float)b[e];
      sn += fa * fb; sq += fa * fa;
    }
  }
  for (int off = 32; off; off >>= 1) {
    sn += __shfl_down(sn, off);
    sq += __shfl_down(sq, off);
  }
  __shared__ float red[8];
  int wid = threadIdx.x >> 6;
  if ((threadIdx.x & 63) == 0) { red[wid] = sn; red[4 + wid] = sq; }
  __syncthreads();
  if (threadIdx.x == 0) {
    part[t * 8 + s]     = red[0] + red[1] + red[2] + red[3];
    part[t * 8 + 4 + s] = red[4] + red[5] + red[6] + red[7];
  }
}

__global__ void k_softmax(float* __restrict__ part) {
  __shared__ float sn_s[128], sq_s[128];
  int t = threadIdx.x;
  if (t < 128) {
    float sn = part[t * 8 + 0] + part[t * 8 + 1] + part[t * 8 + 2] + part[t * 8 + 3];
    float sq = part[t * 8 + 4] + part[t * 8 + 5] + part[t * 8 + 6] + part[t * 8 + 7];
    sn_s[t] = sn; sq_s[t] = sq;
  }
  __syncthreads();
  if (t == 0) {
    float nf = fmaxf(sqrtf(sq_s[127]), 1e-8f);
    float m = -1e30f;
    for (int i = 0; i < TSTEPS; i++) {
      float np = fmaxf(sqrtf(sq_s[i]), 1e-8f);
      sn_s[i] = sn_s[i] / (np * nf);
      m = fmaxf(m, sn_s[i]);
    }
    float ssum = 0.f;
    for (int i = 0; i < TSTEPS; i++) { float e = __expf(sn_s[i] - m); sn_s[i] = e; ssum += e; }
    float inv = 1.f / ssum;
    for (int i = 0; i < TSTEPS; i++) part[1024 + i] = sn_s[i] * inv;
  }
}

__global__ void k_out(const f16* __restrict__ h_all, const float* __restrict__ part,
                      float* __restrict__ out) {
  __shared__ float al[TSTEPS];
  if (threadIdx.x < TSTEPS) al[threadIdx.x] = part[1024 + threadIdx.x];
  __syncthreads();
  int g = blockIdx.x * blockDim.x + threadIdx.x;   // 0..32767
  int kc = g >> 9, row = g & 511;
  float s[8] = {0.f, 0.f, 0.f, 0.f, 0.f, 0.f, 0.f, 0.f};
  for (int t = 1; t < TSTEPS; t++) {               // t=0 is all-zero h0
    f16x8 v = *(const f16x8*)(h_all + (size_t)t * BH + (size_t)kc * 4096 + row * 8);
    float a = al[t];
#pragma unroll
    for (int e = 0; e < 8; e++) s[e] += a * (float)v[e];
  }
  float* o = out + (size_t)row * 512 + kc * 8;
  f32x4 lo = {s[0], s[1], s[2], s[3]}, hi = {s[4], s[5], s[6], s[7]};
  *(f32x4*)o = lo;
  *(f32x4*)(o + 4) = hi;
}

// ---------------------------------------------------------------------------
extern "C" void kernel_launch(void* const* d_in, const int* in_sizes, int n_in,
                              void* d_out, int out_size, void* d_ws, size_t ws_size,
                              hipStream_t stream) {
  const float* X    = (const float*)d_in[0];
  const float* W_ih = (const float*)d_in[1];
  const float* W_hh = (const float*)d_in[2];
  const float* b_ih = (const float*)d_in[3];
  const float* b_hh = (const float*)d_in[4];

  char* ws = (char*)d_ws;
  size_t off = 0;
  auto alloc = [&](size_t bytes) -> void* {
    void* p = ws + off;
    off = (off + bytes + 255) & ~(size_t)255;
    return p;
  };
  f16*   W16B  = (f16*)  alloc((size_t)2048 * 1024 * 2);    // 4 MB
  float* biasR = (float*)alloc(2048 * 4);                   // 8 KB
  f16*   XT    = (f16*)  alloc((size_t)TSTEPS * BH * 2);    // 66 MB
  f16*   h_all = (f16*)  alloc((size_t)T_DIM * BH * 2);     // 64 MB
  float* part  = (float*)alloc(2048 * 4);                   // 8 KB

  hipMemsetAsync(h_all, 0, (size_t)BH * 2, stream);               // h0 = 0
  hipMemsetAsync(h_all + BH, 0xFF, (size_t)TSTEPS * BH * 2, stream); // sentinel

  k_prep_w<<<1024, 256, 0, stream>>>(W_ih, W_hh, W16B);
  k_prep_b<<<8, 256, 0, stream>>>(b_ih, b_hh, biasR);
  k_prep_x<<<dim3(TSTEPS, 16), 256, 0, stream>>>(X, XT);

  k_lstm<<<256, 512, 0, stream>>>(XT, h_all, W16B, biasR);

  k_dots<<<dim3(128, 4), 256, 0, stream>>>(h_all, part);
  k_softmax<<<1, 128, 0, stream>>>(part);
  k_out<<<128, 256, 0, stream>>>(h_all, part, (float*)d_out);
}

// Round 11
// 571.451 us; speedup vs baseline: 1.1056x; 1.1056x over previous
//
#include <hip/hip_runtime.h>
#include <stdint.h>

#define T_DIM  128
#define TSTEPS 127
#define BATCH  512
#define DDATA  512
#define HHID   512
#define BH     262144   // BATCH*HHID
#define CPAD   132      // 16B-aligned rows; conflicts measured small (r6: 2M)

typedef _Float16 f16;
typedef _Float16 f16x8 __attribute__((ext_vector_type(8)));
typedef float    f32x4 __attribute__((ext_vector_type(4)));

#define MFMA16 __builtin_amdgcn_mfma_f32_16x16x32_f16

// asm loads: asm-defined results are non-rematerializable (stay in regs)
__device__ __forceinline__ f16x8 ld16(const f16* p) {          // plain cached
  f16x8 r;
  asm volatile("global_load_dwordx4 %0, %1, off" : "=v"(r) : "v"(p));
  return r;
}
__device__ __forceinline__ f16x8 ld16cc(const f16* p) {        // LLC-coherent (r4/r6-proven)
  f16x8 r;
  asm volatile("global_load_dwordx4 %0, %1, off sc0 sc1" : "=v"(r) : "v"(p));
  return r;
}

// ---------------------------------------------------------------------------
// W16B: f16 B-fragments, flat [nb16][kq4][ch2][fi=ks*4+nf 32][lane64][8]
// col16 = lane&15 = hm*4+g ; k = kq*256 + ks*32 + (lane>>4)*8 + e
// h column hg = nb*32 + (ch*4+nf)*4 + hm ; gate row R = g*512 + hg
// ---------------------------------------------------------------------------
__global__ void k_prep_w(const float* __restrict__ W_ih, const float* __restrict__ W_hh,
                         f16* __restrict__ W16B) {
  int d = blockIdx.x * blockDim.x + threadIdx.x;   // 0..262143
  int lane = d & 63;
  int fi   = (d >> 6) & 31;
  int ch   = (d >> 11) & 1;
  int kq   = (d >> 12) & 3;
  int nbv  = d >> 14;
  int ks = fi >> 2, nf = fi & 3;
  int col16 = lane & 15, lk2 = lane >> 4;
  int hm = col16 >> 2, g = col16 & 3;
  int hg = nbv * 32 + (ch * 4 + nf) * 4 + hm;
  int R = g * 512 + hg;
  int k = kq * 256 + ks * 32 + lk2 * 8;
  const float* src = (k < 512) ? (W_ih + (size_t)R * 512 + k)
                               : (W_hh + (size_t)R * 512 + (k - 512));
  f16x8 o;
#pragma unroll
  for (int e = 0; e < 8; e++) o[e] = (f16)src[e];
  *(f16x8*)(W16B + (size_t)d * 8) = o;
}

__global__ void k_prep_b(const float* __restrict__ b_ih, const float* __restrict__ b_hh,
                         float* __restrict__ biasR) {
  int r = blockIdx.x * blockDim.x + threadIdx.x;
  if (r < 2048) biasR[r] = b_ih[r] + b_hh[r];
}

// X [B, T, D] f32 -> XT [t][kc(64)][row(512)][8] f16, LDS-transposed (r7-proven)
__global__ void k_prep_x(const float* __restrict__ X, f16* __restrict__ XT) {
  __shared__ f16 Ls[32][516];
  const int t = blockIdx.x;
  const int rb = blockIdx.y;
  const int tid = threadIdx.x;
  const int rloc = tid >> 5;
  const int dc = (tid & 31) * 16;
#pragma unroll
  for (int it = 0; it < 4; it++) {
    int row = it * 8 + rloc;
    const float* src = X + (size_t)(rb * 32 + row) * (T_DIM * DDATA)
                         + (size_t)t * DDATA + dc;
    f32x4 a0 = *(const f32x4*)(src);
    f32x4 a1 = *(const f32x4*)(src + 4);
    f32x4 a2 = *(const f32x4*)(src + 8);
    f32x4 a3 = *(const f32x4*)(src + 12);
    f16x8 h0, h1;
#pragma unroll
    for (int e = 0; e < 4; e++) {
      h0[e] = (f16)a0[e]; h0[4 + e] = (f16)a1[e];
      h1[e] = (f16)a2[e]; h1[4 + e] = (f16)a3[e];
    }
    *(f16x8*)&Ls[row][dc] = h0;
    *(f16x8*)&Ls[row][dc + 8] = h1;
  }
  __syncthreads();
#pragma unroll
  for (int it = 0; it < 8; it++) {
    int chunk = it * 256 + tid;
    int kc = chunk >> 5, row = chunk & 31;
    f16x8 v = *(const f16x8*)&Ls[row][kc * 8];
    *(f16x8*)(XT + (size_t)t * BH + (size_t)kc * 4096
              + (size_t)(rb * 32 + row) * 8) = v;
  }
}

// ---------------------------------------------------------------------------
// Persistent LSTM: 256 WGs x 512 thr. r6-PROVEN protocol, verbatim:
// - one 64B flag line per (mb,t); tid0 AGENT-relaxed add AFTER full vmcnt
//   drain + __syncthreads (all h stores ACKed at LLC before signal).
// - h-side: wave4.lane0 leader-polls the flag line, relays via LDS goS.
// - h data: sc0sc1 (LLC-coherent) loads/stores only.
// Epilogue: r4-PROVEN 512-thread version (2 h-cols/thread, c0/c1 in regs).
// Waves: w>>1 = kq (K-quarter; 0,1 = x-half, 2,3 = h-half), w&1 = ch.
// ---------------------------------------------------------------------------
__launch_bounds__(512, 1)
__global__ void k_lstm(const f16* __restrict__ XT, f16* __restrict__ h_all,
                       const f16* __restrict__ W16B, const float* __restrict__ biasR,
                       int* __restrict__ done) {
  __shared__ float C[4][32][CPAD];     // per-K-quarter partials (~67.6KB)
  __shared__ int goS;

  const int tid = threadIdx.x, lane = tid & 63, w = tid >> 6;
  const int kq = w >> 1;
  const int wg = blockIdx.x;
  const int mb = (wg & 7) * 2 + ((wg >> 3) & 1);
  const int nb = wg >> 4;
  const int m0 = mb * 32;
  const int l15 = lane & 15, lk = lane >> 4;

  // persistent B fragments: 32 x f16x8 = 128 regs/wave, pinned by asm defs
  f16x8 B[32];
  {
    const f16* wb = W16B + ((size_t)((nb * 4 + kq) * 2 + (w & 1)) * 32) * 512 + lane * 8;
#pragma unroll
    for (int i = 0; i < 32; i++) B[i] = ld16(wb + i * 512);
    asm volatile("s_waitcnt vmcnt(0)" ::: "memory");
    __builtin_amdgcn_sched_barrier(0);
  }
  // r4-proven epilogue mapping: thread -> (row rloc, h-col pair 2hp, 2hp+1)
  const int rloc = tid >> 4, hp = tid & 15;
  const int hg0 = nb * 32 + 2 * hp;
  float bv[8];
#pragma unroll
  for (int e = 0; e < 8; e++)
    bv[e] = biasR[(e & 3) * 512 + nb * 32 + 2 * hp + (e >> 2)];
  float c0 = 0.f, c1 = 0.f;
  unsigned int* hdst_base = (unsigned int*)(h_all
      + (size_t)(hg0 >> 3) * 4096 + (size_t)(m0 + rloc) * 8 + (hg0 & 7));
  if (tid == 0) goS = 0;
  __syncthreads();

#define WAITV(N) asm volatile("s_waitcnt vmcnt(" #N ")" ::: "memory");        \
                 __builtin_amdgcn_sched_barrier(0)
#define MFMA4KS(KS0)                                                          \
    {                                                                         \
      _Pragma("unroll")                                                       \
      for (int s = 0; s < 4; s++) {                                           \
        int ks = KS0 + s;                                                     \
        _Pragma("unroll")                                                     \
        for (int nf = 0; nf < 4; nf++) {                                      \
          acc[0][nf] = MFMA16(R[2 * ks],     B[ks * 4 + nf], acc[0][nf], 0, 0, 0); \
          acc[1][nf] = MFMA16(R[2 * ks + 1], B[ks * 4 + nf], acc[1][nf], 0, 0, 0); \
        }                                                                     \
      }                                                                       \
    }
#define ISSUE_X(T)                                                            \
    {                                                                         \
      const f16* Ab = XT + (size_t)(T) * BH + (size_t)(kq * 32 + lk) * 4096   \
                      + (size_t)(m0 + l15) * 8;                               \
      _Pragma("unroll")                                                       \
      for (int ks = 0; ks < 8; ks++) {                                        \
        R[2 * ks]     = ld16(Ab + (size_t)ks * 16384);                        \
        R[2 * ks + 1] = ld16(Ab + (size_t)ks * 16384 + 128);                  \
      }                                                                       \
    }

  f16x8 R[16];
  if (kq < 2) ISSUE_X(0);              // prologue prefetch for t=0

  for (int t = 0; t < TSTEPS; t++) {
    f32x4 acc[2][4] = {};

    if (kq < 2) {
      // x-half: loads for this t were prefetched last iteration (drained at
      // the previous barrier -> data already in R; WAITV(0) is a cheap no-op)
      WAITV(0);
      MFMA4KS(0);
      MFMA4KS(4);
      if (t + 1 < TSTEPS) ISSUE_X(t + 1);   // completes under the barrier drain
    } else if (t > 0) {
      // h-half: leader polls LLC flag; others spin on LDS go-word (r6-proven)
      if (w == 4) {
        if (lane == 0) {
          const int* flag = done + (size_t)(mb * 128 + (t - 1)) * 16;
          int spins = 0;
          while (__hip_atomic_load(flag, __ATOMIC_RELAXED, __HIP_MEMORY_SCOPE_AGENT) < 16) {
            __builtin_amdgcn_s_sleep(1);
            if (++spins > (1 << 20)) break;   // bounded: fail visibly, no watchdog
          }
          __hip_atomic_store(&goS, t, __ATOMIC_RELAXED, __HIP_MEMORY_SCOPE_WORKGROUP);
        }
      } else {
        int spins = 0;
        while (__hip_atomic_load(&goS, __ATOMIC_RELAXED, __HIP_MEMORY_SCOPE_WORKGROUP) < t) {
          __builtin_amdgcn_s_sleep(1);
          if (++spins > (1 << 20)) break;
        }
      }
      const f16* Hb = h_all + (size_t)t * BH + (size_t)((kq - 2) * 32 + lk) * 4096
                      + (size_t)(m0 + l15) * 8;
#pragma unroll
      for (int ks = 0; ks < 8; ks++) {
        R[2 * ks]     = ld16cc(Hb + (size_t)ks * 16384);
        R[2 * ks + 1] = ld16cc(Hb + (size_t)ks * 16384 + 128);
      }
      WAITV(8);  MFMA4KS(0);
      WAITV(0);  MFMA4KS(4);
    }
    // (kq>=2, t==0: h0 == 0 -> acc stays zero)

    // K-quarter partials -> LDS
#pragma unroll
    for (int mf = 0; mf < 2; mf++)
#pragma unroll
      for (int nf = 0; nf < 4; nf++)
#pragma unroll
        for (int r = 0; r < 4; r++)
          C[kq][mf * 16 + lk * 4 + r][(w & 1) * 64 + nf * 16 + l15] = acc[mf][nf][r];
    __syncthreads();

    // 512-thread epilogue (r4-proven): sum 4 quarters, cell update, 4B store
    {
      f32x4 u0 = {0.f, 0.f, 0.f, 0.f}, u1 = {0.f, 0.f, 0.f, 0.f};
#pragma unroll
      for (int q = 0; q < 4; q++) {
        u0 += *(const f32x4*)&C[q][rloc][hp * 8];
        u1 += *(const f32x4*)&C[q][rloc][hp * 8 + 4];
      }
      float gi0 = u0[0] + bv[0];
      float gf0 = u0[1] + bv[1];
      float gg0 = u0[2] + bv[2];
      float go0 = u0[3] + bv[3];
      float gi1 = u1[0] + bv[4];
      float gf1 = u1[1] + bv[5];
      float gg1 = u1[2] + bv[6];
      float go1 = u1[3] + bv[7];

      float i0 = 1.f / (1.f + __expf(-gi0));
      float f0 = 1.f / (1.f + __expf(-gf0));
      float e0 = __expf(-2.f * fabsf(gg0));
      float tg0 = copysignf((1.f - e0) / (1.f + e0), gg0);
      float o0 = 1.f / (1.f + __expf(-go0));
      c0 = f0 * c0 + i0 * tg0;
      float ec0 = __expf(-2.f * fabsf(c0));
      float th0 = copysignf((1.f - ec0) / (1.f + ec0), c0);
      float h0 = o0 * th0;

      float i1 = 1.f / (1.f + __expf(-gi1));
      float f1 = 1.f / (1.f + __expf(-gf1));
      float e1 = __expf(-2.f * fabsf(gg1));
      float tg1 = copysignf((1.f - e1) / (1.f + e1), gg1);
      float o1 = 1.f / (1.f + __expf(-go1));
      c1 = f1 * c1 + i1 * tg1;
      float ec1 = __expf(-2.f * fabsf(c1));
      float th1 = copysignf((1.f - ec1) / (1.f + ec1), c1);
      float h1 = o1 * th1;

      union { f16 h[2]; unsigned int u; } pk;
      pk.h[0] = (f16)h0; pk.h[1] = (f16)h1;
      __hip_atomic_store(hdst_base + (size_t)(t + 1) * (BH / 2), pk.u,
                         __ATOMIC_RELAXED, __HIP_MEMORY_SCOPE_AGENT);
    }
    // r6-proven signal: all stores ACKed at LLC (vmcnt drain) -> barrier ->
    // single AGENT-relaxed add by tid0.
    asm volatile("s_waitcnt vmcnt(0)" ::: "memory");
    __syncthreads();
    if (tid == 0)
      __hip_atomic_fetch_add(done + (size_t)(mb * 128 + t) * 16, 1,
                             __ATOMIC_RELAXED, __HIP_MEMORY_SCOPE_AGENT);
  }
#undef WAITV
#undef MFMA4KS
#undef ISSUE_X
}

// ---------------------------------------------------------------------------
// Tail: cosine-similarity attention (h_all is f16) — r6 verbatim
// ---------------------------------------------------------------------------
__global__ void k_dots(const f16* __restrict__ h_all, float* __restrict__ part) {
  int t = blockIdx.x, s = blockIdx.y;
  const f16x8* ht = (const f16x8*)(h_all + (size_t)t * BH) + (size_t)s * 8192;
  const f16x8* hf = (const f16x8*)(h_all + (size_t)127 * BH) + (size_t)s * 8192;
  float sn = 0.f, sq = 0.f;
  for (int i = threadIdx.x; i < 8192; i += 256) {
    f16x8 a = ht[i], b = hf[i];
#pragma unroll
    for (int e = 0; e < 8; e++) {
      float fa = (float)a[e], fb = (float)b[e];
      sn += fa * fb; sq += fa * fa;
    }
  }
  for (int off = 32; off; off >>= 1) {
    sn += __shfl_down(sn, off);
    sq += __shfl_down(sq, off);
  }
  __shared__ float red[8];
  int wid = threadIdx.x >> 6;
  if ((threadIdx.x & 63) == 0) { red[wid] = sn; red[4 + wid] = sq; }
  __syncthreads();
  if (threadIdx.x == 0) {
    part[t * 8 + s]     = red[0] + red[1] + red[2] + red[3];
    part[t * 8 + 4 + s] = red[4] + red[5] + red[6] + red[7];
  }
}

__global__ void k_softmax(float* __restrict__ part) {
  __shared__ float sn_s[128], sq_s[128];
  int t = threadIdx.x;
  if (t < 128) {
    float sn = part[t * 8 + 0] + part[t * 8 + 1] + part[t * 8 + 2] + part[t * 8 + 3];
    float sq = part[t * 8 + 4] + part[t * 8 + 5] + part[t * 8 + 6] + part[t * 8 + 7];
    sn_s[t] = sn; sq_s[t] = sq;
  }
  __syncthreads();
  if (t == 0) {
    float nf = fmaxf(sqrtf(sq_s[127]), 1e-8f);
    float m = -1e30f;
    for (int i = 0; i < TSTEPS; i++) {
      float np = fmaxf(sqrtf(sq_s[i]), 1e-8f);
      sn_s[i] = sn_s[i] / (np * nf);
      m = fmaxf(m, sn_s[i]);
    }
    float ssum = 0.f;
    for (int i = 0; i < TSTEPS; i++) { float e = __expf(sn_s[i] - m); sn_s[i] = e; ssum += e; }
    float inv = 1.f / ssum;
    for (int i = 0; i < TSTEPS; i++) part[1024 + i] = sn_s[i] * inv;
  }
}

__global__ void k_out(const f16* __restrict__ h_all, const float* __restrict__ part,
                      float* __restrict__ out) {
  __shared__ float al[TSTEPS];
  if (threadIdx.x < TSTEPS) al[threadIdx.x] = part[1024 + threadIdx.x];
  __syncthreads();
  int g = blockIdx.x * blockDim.x + threadIdx.x;   // 0..32767
  int kc = g >> 9, row = g & 511;
  float s[8] = {0.f, 0.f, 0.f, 0.f, 0.f, 0.f, 0.f, 0.f};
  for (int t = 1; t < TSTEPS; t++) {               // t=0 is all-zero h0
    f16x8 v = *(const f16x8*)(h_all + (size_t)t * BH + (size_t)kc * 4096 + row * 8);
    float a = al[t];
#pragma unroll
    for (int e = 0; e < 8; e++) s[e] += a * (float)v[e];
  }
  float* o = out + (size_t)row * 512 + kc * 8;
  f32x4 lo = {s[0], s[1], s[2], s[3]}, hi = {s[4], s[5], s[6], s[7]};
  *(f32x4*)o = lo;
  *(f32x4*)(o + 4) = hi;
}

// ---------------------------------------------------------------------------
extern "C" void kernel_launch(void* const* d_in, const int* in_sizes, int n_in,
                              void* d_out, int out_size, void* d_ws, size_t ws_size,
                              hipStream_t stream) {
  const float* X    = (const float*)d_in[0];
  const float* W_ih = (const float*)d_in[1];
  const float* W_hh = (const float*)d_in[2];
  const float* b_ih = (const float*)d_in[3];
  const float* b_hh = (const float*)d_in[4];

  char* ws = (char*)d_ws;
  size_t off = 0;
  auto alloc = [&](size_t bytes) -> void* {
    void* p = ws + off;
    off = (off + bytes + 255) & ~(size_t)255;
    return p;
  };
  f16*   W16B  = (f16*)  alloc((size_t)2048 * 1024 * 2);    // 4 MB
  float* biasR = (float*)alloc(2048 * 4);                   // 8 KB
  f16*   XT    = (f16*)  alloc((size_t)TSTEPS * BH * 2);    // 66 MB
  f16*   h_all = (f16*)  alloc((size_t)T_DIM * BH * 2);     // 64 MB
  int*   done  = (int*)  alloc(16 * 128 * 64);              // 128 KB (64B line per mb,t)
  float* part  = (float*)alloc(2048 * 4);                   // 8 KB

  hipMemsetAsync(h_all, 0, (size_t)BH * 2, stream);   // h0 = 0
  hipMemsetAsync(done,  0, 16 * 128 * 64, stream);

  k_prep_w<<<1024, 256, 0, stream>>>(W_ih, W_hh, W16B);
  k_prep_b<<<8, 256, 0, stream>>>(b_ih, b_hh, biasR);
  k_prep_x<<<dim3(TSTEPS, 16), 256, 0, stream>>>(X, XT);

  k_lstm<<<256, 512, 0, stream>>>(XT, h_all, W16B, biasR, done);

  k_dots<<<dim3(128, 4), 256, 0, stream>>>(h_all, part);
  k_softmax<<<1, 128, 0, stream>>>(part);
  k_out<<<128, 256, 0, stream>>>(h_all, part, (float*)d_out);
}